// Round 2
// baseline (221.985 us; speedup 1.0000x reference)
//
#include <hip/hip_runtime.h>
#include <hip/hip_bf16.h>

// RandScatter with a CONSTANT score matrix:
//   score.argmax(axis=1) = [0, 1, 1, 1]
//   path 0 <- token 0            -> out chunk 0 = inputs[0:1, :]
//   path 1 <- tokens 1, 2, 3     -> out chunk 1 = inputs[1:4, :]
// Concatenated flat output = tokens [0,1,2,3] in order = the input, verbatim.
// The entire op is a 128 MiB fp32 D2D copy. Memory-bound; use the blit copy.

// Fallback vectorized copy kernel (not used by default, kept for reference):
__global__ void copy_f4_kernel(const float4* __restrict__ src,
                               float4* __restrict__ dst, long n4) {
    long i = (long)blockIdx.x * blockDim.x + threadIdx.x;
    long stride = (long)gridDim.x * blockDim.x;
    for (; i < n4; i += stride) dst[i] = src[i];
}

extern "C" void kernel_launch(void* const* d_in, const int* in_sizes, int n_in,
                              void* d_out, int out_size, void* d_ws, size_t ws_size,
                              hipStream_t stream) {
    (void)n_in; (void)d_ws; (void)ws_size;
    const float* in = (const float*)d_in[0];
    float* out = (float*)d_out;
    // out_size == in_sizes[0] == 4 * 8388608 fp32 elements.
    size_t bytes = (size_t)out_size * sizeof(float);
    hipMemcpyAsync(out, in, bytes, hipMemcpyDeviceToDevice, stream);
}